// Round 7
// baseline (412.046 us; speedup 1.0000x reference)
//
#include <hip/hip_runtime.h>

#define DEV __device__ __forceinline__

// Problem constants
constexpr int Cc = 64, DIc = 128, Sc = 16, Rc = 4, Kc = 4;
constexpr int Lc = 2304, Tc = 4;
constexpr int NCH = 288, CHL = 8;  // 288 chunks of 8 (halved chain vs r6)

// Workspace layout (float offsets). 5 slots: 0-3 = bias branch t=0..3, 4 = s-branch.
constexpr int OFF_XCPRE = 0;              // L*DI  [l][d]
constexpr int OFF_Z     = 294912;         // L*DI  [l][d]
constexpr int OFF_XACT  = 589824;         // L*DI  [l][d]
constexpr int OFF_DTS   = 884736;         // K*L*R [k][pos][r]  (r contiguous -> float4)
constexpr int OFF_BS    = 921600;         // K*L*S [k][pos][s]
constexpr int OFF_CS    = 1069056;        // K*L*S
constexpr int OFF_Y     = 1216512;        // 2*L*DI [pair][pixel][d] (dir-pairs pre-combined)
constexpr int OFF_SUMA  = 1806336;        // K*NCH*S*DI (lane-major in d) = 2359296
constexpr int OFF_SUMB  = 4165632;
constexpr int OFF_H0    = 6524928;
constexpr int SLOTF     = 8884224;
constexpr int OFF_B1    = 5 * SLOTF;      // L*C state buffers [l][c]
constexpr int OFF_B2    = OFF_B1 + Lc * Cc;
constexpr int OFF_BIAS  = OFF_B2 + Lc * Cc;       // T*L*C [t][l][c]
// Lane-major transposed weights:
constexpr int OFF_TW    = OFF_BIAS + Tc * Lc * Cc;
constexpr int TW_INW  = 0;        // [2][64][256]
constexpr int TW_XPW  = 32768;    // [2][128][144]
constexpr int TW_OW   = 69632;    // [2][128][64]
constexpr int TW_CW   = 86016;    // [2][9][128]
constexpr int TW_AT   = 88320;    // [2][4][16][128]  (stores A2 = -exp(A_logs)*log2e)
constexpr int TW_DTW  = 104704;   // [2][4][4][128]

struct Params {
  const float *img, *dz, *sigma, *in_w, *in_b, *conv_w, *conv_b, *xp_w, *dt_w,
              *dt_b, *A_logs, *Ds, *onw, *onb, *ow, *ob, *niw, *nib, *ndw, *ndb;
  float* outp;
  float* ws;
};

DEV float wsum(float v) {
#pragma unroll
  for (int m = 32; m; m >>= 1) v += __shfl_xor(v, m, 64);
  return v;
}
DEV float wmax(float v) {
#pragma unroll
  for (int m = 32; m; m >>= 1) v = fmaxf(v, __shfl_xor(v, m, 64));
  return v;
}
DEV float sigmoidf(float x) { return 1.f / (1.f + __expf(-x)); }
DEV float softplusf(float v) { return (v > 20.f) ? v : __logf(1.f + __expf(v)); }
DEV float fexp2(float x) { return __builtin_amdgcn_exp2f(x); }

// scan-position -> row-major pixel index, per direction
DEV int perm_idx(int k, int l) {
  if (k == 0) return l;
  if (k == 1) return (l % 48) * 48 + l / 48;
  if (k == 2) return Lc - 1 - l;
  int pp = Lc - 1 - l;
  return (pp % 48) * 48 + pp / 48;
}

// Within one 8-chunk the pixel index is base + stride*i (48 % 8 == 0, no wrap).
DEV int perm_stride(int k) {
  return (k == 0) ? 1 : (k == 1) ? 48 : (k == 2) ? -1 : -48;
}

// ---------------------------------------------------------------------------
// one-time: transpose weights into lane-major layouts. grid 144.
__global__ __launch_bounds__(256) void g_transpose(Params p) {
  float* tw = p.ws + OFF_TW;
  int i = blockIdx.x * 256 + threadIdx.x;
  if (i < 32768) {  // inwT
    int d = i & 255, cc = (i >> 8) & 63, b = i >> 14;
    tw[TW_INW + i] = p.in_w[(b * 256 + d) * 64 + cc];
  }
  if (i < 36864) {  // xpwT
    int kr = i % 144, cc = (i / 144) & 127, b = i / (144 * 128);
    tw[TW_XPW + i] = p.xp_w[(b * 144 + kr) * 128 + cc];
  }
  if (i < 16384) {  // owT
    int c = i & 63, d = (i >> 6) & 127, b = i >> 13;
    tw[TW_OW + i] = p.ow[(b * 64 + c) * 128 + d];
  }
  if (i < 2304) {   // cwT
    int d = i & 127, kk = (i >> 7) % 9, b = i / 1152;
    tw[TW_CW + i] = p.conv_w[(b * 128 + d) * 9 + kk];
  }
  if (i < 16384) {  // A2 = -exp(A_logs) * log2(e)  (exp2-folded)
    int d = i & 127, bks = i >> 7;
    int s = bks & 15, bk = bks >> 4;
    tw[TW_AT + i] = -__expf(p.A_logs[(bk * 128 + d) * 16 + s]) * 1.4426950408889634f;
  }
  if (i < 4096) {   // dtwT
    int d = i & 127, bkr = i >> 7;
    int r = bkr & 3, bk = bkr >> 2;
    tw[TW_DTW + i] = p.dt_w[(bk * 128 + d) * 4 + r];
  }
}

// ---------------------------------------------------------------------------
// mega input projection, grid (288, 5). slots 0-3: x = LN_c(img[slot]) (branch 1);
// slot 4: fused prep — pv = LN_c(dz), cv = pv*exp(sigma) -> B1, x = KL(cv, pv).
__global__ __launch_bounds__(256) void g_inproj(Params p) {
  __shared__ float xv[8][64];
  int tid = threadIdx.x;
  int slot = blockIdx.y;
  int branch = (slot >= 4) ? 0 : 1;
  float* ws = p.ws;
  float* base = ws + (size_t)slot * SLOTF;
  float* xcpre = base + OFF_XCPRE;
  float* zbuf  = base + OFF_Z;
  const float* wT = ws + OFF_TW + TW_INW + branch * 64 * 256;
  int l0 = blockIdx.x * 8;
  int wv = tid >> 6, c = tid & 63;
#pragma unroll
  for (int q = 0; q < 2; q++) {
    int pp = wv * 2 + q;
    int l = l0 + pp;
    float x;
    if (branch == 1) {
      float v = p.img[(slot * Cc + c) * Lc + l];
      float mu = wsum(v) * (1.f / 64.f);
      float var = wsum(v * v) * (1.f / 64.f) - mu * mu;
      x = (v - mu) * rsqrtf(var + 1e-6f) * p.niw[c] + p.nib[c];
    } else {
      // fused prep: prev = LN_c(dz), cur = prev*exp(sigma)
      float v = p.dz[c * Lc + l];
      float mu = wsum(v) * (1.f / 64.f);
      float var = wsum(v * v) * (1.f / 64.f) - mu * mu;
      float pv = (v - mu) * rsqrtf(var + 1e-6f) * p.ndw[c] + p.ndb[c];
      float cv = pv * __expf(p.sigma[c * Lc + l]);
      (ws + OFF_B1)[l * Cc + c] = cv;
      float mp = wmax(pv);
      float sp = wsum(__expf(pv - mp));
      float lp = pv - mp - __logf(sp);
      float mq = wmax(cv);
      float sq = wsum(__expf(cv - mq));
      float lq = cv - mq - __logf(sq);
      x = __expf(lp) * (lp - lq);
    }
    xv[pp][c] = x;
  }
  __syncthreads();
  int d = tid;
  float acc[8];
#pragma unroll
  for (int q = 0; q < 8; q++) acc[q] = 0.f;
  for (int cc = 0; cc < Cc; cc++) {
    float wval = wT[cc * 256 + d];
#pragma unroll
    for (int q = 0; q < 8; q++) acc[q] += wval * xv[q][cc];
  }
  float bv = p.in_b[branch * 2 * DIc + d];
  if (d < DIc) {
#pragma unroll
    for (int q = 0; q < 8; q++) xcpre[(l0 + q) * DIc + d] = acc[q] + bv;
  } else {
    int dd = d - DIc;
#pragma unroll
    for (int q = 0; q < 8; q++) zbuf[(l0 + q) * DIc + dd] = acc[q] + bv;
  }
}

// ---------------------------------------------------------------------------
// depthwise conv3x3 + silu -> xact; xp proj -> dts/Bs/Cs. grid (576, nslots).
__global__ __launch_bounds__(256) void g_conv(Params p, int slot_base) {
  __shared__ float xv[4][DIc];
  int tid = threadIdx.x;
  int slot = slot_base + blockIdx.y;
  int branch = (slot >= 4) ? 0 : 1;
  float* ws = p.ws;
  float* base = ws + (size_t)slot * SLOTF;
  float* xcpre = base + OFF_XCPRE;
  float* xact  = base + OFF_XACT;
  float* dtsb  = base + OFF_DTS;
  float* Bsb   = base + OFF_BS;
  float* Csb   = base + OFF_CS;
  const float* cwT  = ws + OFF_TW + TW_CW + branch * 9 * 128;
  const float* xpwT = ws + OFF_TW + TW_XPW + branch * 128 * 144;
  int h = blockIdx.x / 12;
  int w0 = (blockIdx.x % 12) * 4;
  for (int it = tid; it < 4 * DIc; it += 256) {
    int d = it & (DIc - 1);
    int pp = it >> 7;
    int w = w0 + pp;
    float acc = 0.f;
#pragma unroll
    for (int kh = 0; kh < 3; kh++) {
      int hh = h + kh - 1;
      if ((unsigned)hh < 48u) {
#pragma unroll
        for (int kw = 0; kw < 3; kw++) {
          int wp = w + kw - 1;
          if ((unsigned)wp < 48u)
            acc += cwT[(kh * 3 + kw) * 128 + d] * xcpre[(hh * 48 + wp) * DIc + d];
        }
      }
    }
    float v = acc + p.conv_b[branch * DIc + d];
    float s = v * sigmoidf(v);
    xv[pp][d] = s;
    xact[(h * 48 + w) * DIc + d] = s;
  }
  __syncthreads();
  if (tid < Kc * 36) {
    int k = tid / 36, r = tid % 36;
    float acc[4] = {0.f, 0.f, 0.f, 0.f};
    for (int cc = 0; cc < DIc; cc++) {
      float wvv = xpwT[cc * 144 + tid];
#pragma unroll
      for (int pp = 0; pp < 4; pp++) acc[pp] += wvv * xv[pp][cc];
    }
#pragma unroll
    for (int pp = 0; pp < 4; pp++) {
      int w = w0 + pp;
      int lr = h * 48 + w, lcx = w * 48 + h;
      int pos = (k == 0) ? lr : (k == 1) ? lcx : (k == 2) ? (Lc - 1 - lr) : (Lc - 1 - lcx);
      if (r < Rc) dtsb[(k * Lc + pos) * Rc + r] = acc[pp];
      else if (r < Rc + Sc) Bsb[(k * Lc + pos) * Sc + (r - Rc)] = acc[pp];
      else Csb[(k * Lc + pos) * Sc + (r - Rc - Sc)] = acc[pp];
    }
  }
}

// ---------------------------------------------------------------------------
// scan pass 1: per-chunk summaries. Chunk = 8 positions. Block = (k,ch,shb):
// 128 d x 2 s-quarters, 4 s-states/thread, 8-step chain.
// Grid (K*NCH*2 = 2304, nslots). LDS 0.5KB.
__global__ __launch_bounds__(256, 4) void g_scan1(Params p, int slot_base) {
  __shared__ alignas(16) float sB[CHL * Sc];  // 512B
  int tid = threadIdx.x;
  int slot = slot_base + blockIdx.y;
  int branch = (slot >= 4) ? 0 : 1;
  float* ws = p.ws;
  float* base = ws + (size_t)slot * SLOTF;
  const float* xact = base + OFF_XACT;
  const float* Bsb  = base + OFF_BS;
  const float* dtsb = base + OFF_DTS;
  float* sumA = base + OFF_SUMA;
  float* sumB = base + OFF_SUMB;
  int bx = blockIdx.x;
  int shb = bx & 1;
  int kch = bx >> 1;
  int k = kch / NCH, ch = kch - k * NCH;
  int d = tid & (DIc - 1);
  int sq = tid >> 7;
  int s0 = shb * 8 + sq * 4;  // this thread's 4 s-states
  int bk = branch * Kc + k;
  const float* AT   = ws + OFF_TW + TW_AT;
  const float* dtwT = ws + OFF_TW + TW_DTW;
  int l0 = ch * CHL;
  // stage chunk B (128 floats)
  if (tid < CHL * Sc) sB[tid] = Bsb[(k * Lc + l0) * Sc + tid];
  float A2[4];
#pragma unroll
  for (int j = 0; j < 4; j++) A2[j] = AT[(bk * 16 + s0 + j) * 128 + d];
  float dw0 = dtwT[(bk * 4 + 0) * 128 + d];
  float dw1 = dtwT[(bk * 4 + 1) * 128 + d];
  float dw2 = dtwT[(bk * 4 + 2) * 128 + d];
  float dw3 = dtwT[(bk * 4 + 3) * 128 + d];
  float db = p.dt_b[bk * DIc + d];
  int idx0 = perm_idx(k, l0);
  int st = perm_stride(k);
  float dtv[CHL], dtx[CHL];
  float CT = 0.f;
#pragma unroll
  for (int i = 0; i < CHL; i++) {
    float4 dt4 = *(const float4*)(dtsb + (size_t)(k * Lc + l0 + i) * 4);
    float v = db + dw0 * dt4.x + dw1 * dt4.y + dw2 * dt4.z + dw3 * dt4.w;
    float t = softplusf(v);
    dtv[i] = t;
    dtx[i] = t * xact[(idx0 + st * i) * DIc + d];
    CT += t;
  }
  __syncthreads();
  const float4* B4 = (const float4*)sB;
  float h[4];
#pragma unroll
  for (int j = 0; j < 4; j++) h[j] = 0.f;
#pragma unroll
  for (int i = 0; i < CHL; i++) {
    float4 Bg = B4[i * 4 + (s0 >> 2)];
    float t = dtv[i], tx = dtx[i];
#define STEP1(hh, bb, aa2) { float da = fexp2(t * (aa2)); hh = da * hh + tx * (bb); }
    STEP1(h[0], Bg.x, A2[0]);
    STEP1(h[1], Bg.y, A2[1]);
    STEP1(h[2], Bg.z, A2[2]);
    STEP1(h[3], Bg.w, A2[3]);
#undef STEP1
  }
  float* sa = sumA + ((size_t)(k * NCH + ch) * Sc + s0) * DIc + d;
  float* sb = sumB + ((size_t)(k * NCH + ch) * Sc + s0) * DIc + d;
#pragma unroll
  for (int j = 0; j < 4; j++) sa[j * DIc] = fexp2(A2[j] * CT);  // == prod_i da_i
#pragma unroll
  for (int j = 0; j < 4; j++) sb[j * DIc] = h[j];
}

// ---------------------------------------------------------------------------
// scan mid, parallelized: chain of 288 = 16 groups x 18. Block = 256 thr
// (16 d-lanes x 16 groups). Serial 18-aggregate, Kogge-Stone over 16 group
// aggregates in LDS (4 steps), re-scan 18 from registers.
// Grid (Kc*Sc*8 dblk = 512, nslots).
__global__ __launch_bounds__(256) void g_mid(Params p, int slot_base) {
  __shared__ float sA[16][17], sBs[16][17];
  int tid = threadIdx.x;
  int slot = slot_base + blockIdx.y;
  float* base = p.ws + (size_t)slot * SLOTF;
  const float* sumA = base + OFF_SUMA;
  const float* sumB = base + OFF_SUMB;
  float* h0 = base + OFF_H0;
  int bx = blockIdx.x;     // k*128 + s*8 + dblk
  int k = bx >> 7;
  int s = (bx >> 3) & 15;
  int dblk = bx & 7;
  int dl = tid & 15;
  int g = tid >> 4;        // group 0..15 (18 chunks each)
  int d = dblk * 16 + dl;
  float a[18], b[18];
#pragma unroll
  for (int j = 0; j < 18; j++) {
    size_t idx = ((size_t)(k * NCH + g * 18 + j) * Sc + s) * DIc + d;
    a[j] = sumA[idx];
    b[j] = sumB[idx];
  }
  // group aggregate (apply chunks in order): h' = Ag*h + Bg
  float Ag = 1.f, Bg = 0.f;
#pragma unroll
  for (int j = 0; j < 18; j++) { Bg = a[j] * Bg + b[j]; Ag *= a[j]; }
  sA[g][dl] = Ag; sBs[g][dl] = Bg;
  __syncthreads();
  // inclusive Kogge-Stone over groups
  float Ai = Ag, Bi = Bg;
#pragma unroll
  for (int off = 1; off < 16; off <<= 1) {
    float Ap = 1.f, Bp = 0.f;
    bool take = (g >= off);
    if (take) { Ap = sA[g - off][dl]; Bp = sBs[g - off][dl]; }
    __syncthreads();
    if (take) {
      Bi = Ai * Bp + Bi;
      Ai = Ai * Ap;
      sA[g][dl] = Ai; sBs[g][dl] = Bi;
    }
    __syncthreads();
  }
  // exclusive prefix applied to h_init=0 -> B_inclusive(g-1)
  float h = (g == 0) ? 0.f : sBs[g - 1][dl];
#pragma unroll
  for (int j = 0; j < 18; j++) {
    size_t idx = ((size_t)(k * NCH + g * 18 + j) * Sc + s) * DIc + d;
    h0[idx] = h;
    h = a[j] * h + b[j];
  }
}

// ---------------------------------------------------------------------------
// scan pass 2: dir-pair merged, d split in half, 8-step chain. Block = 256
// thr (64 d x 2 sh x 2 dir), wave-aligned roles. Grid (2 pair x NCH x 2 dblk
// = 1152, nslots). LDS 6KB; dtv/dtx recomputed per thread.
__global__ __launch_bounds__(256, 4) void g_scan2(Params p, int slot_base) {
  __shared__ alignas(16) float sB[2][CHL * Sc];   // 1KB
  __shared__ alignas(16) float sC[2][CHL * Sc];   // 1KB
  __shared__ alignas(16) float yred[2][CHL][64];  // 4KB
  int tid = threadIdx.x;
  int slot = slot_base + blockIdx.y;
  int branch = (slot >= 4) ? 0 : 1;
  float* ws = p.ws;
  float* base = ws + (size_t)slot * SLOTF;
  const float* xact = base + OFF_XACT;
  const float* Bsb  = base + OFF_BS;
  const float* Csb  = base + OFF_CS;
  const float* dtsb = base + OFF_DTS;
  const float* h0b  = base + OFF_H0;
  int bx = blockIdx.x;
  int pair = bx / (2 * NCH);
  int rem = bx - pair * 2 * NCH;
  int chA = rem >> 1;
  int dblk = rem & 1;
  int dm = tid & 63;
  int d = dblk * 64 + dm;
  int sh = (tid >> 6) & 1;
  int dir = tid >> 7;
  int kA = pair, kB = pair + 2;
  int l0A = chA * CHL, l0B = (NCH - 1 - chA) * CHL;
  // stage both dirs' B/C (each thread: 1 B + 1 C load)
  {
    int sdir = tid >> 7, soff = tid & 127;
    int ks = sdir ? kB : kA, l0s = sdir ? l0B : l0A;
    sB[sdir][soff] = Bsb[(ks * Lc + l0s) * Sc + soff];
    sC[sdir][soff] = Csb[(ks * Lc + l0s) * Sc + soff];
  }
  int k = dir ? kB : kA;
  int ch = dir ? (NCH - 1 - chA) : chA;
  int bk = branch * Kc + k;
  float* ypair = base + OFF_Y + (size_t)pair * Lc * DIc;
  const float* AT   = ws + OFF_TW + TW_AT;
  const float* dtwT = ws + OFF_TW + TW_DTW;
  int l0 = ch * CHL;
  float A2[8];
#pragma unroll
  for (int j = 0; j < 8; j++) A2[j] = AT[(bk * 16 + sh * 8 + j) * 128 + d];
  float h[8];
  {
    const float* hp = h0b + ((size_t)(k * NCH + ch) * Sc + sh * 8) * DIc + d;
#pragma unroll
    for (int j = 0; j < 8; j++) h[j] = hp[j * DIc];
  }
  float dw0 = dtwT[(bk * 4 + 0) * 128 + d];
  float dw1 = dtwT[(bk * 4 + 1) * 128 + d];
  float dw2 = dtwT[(bk * 4 + 2) * 128 + d];
  float dw3 = dtwT[(bk * 4 + 3) * 128 + d];
  float db = p.dt_b[bk * DIc + d];
  float Dv = p.Ds[bk * DIc + d];
  int idx0 = perm_idx(k, l0);
  int st = perm_stride(k);
  float dtv[CHL], dtx[CHL], acc[CHL];
#pragma unroll
  for (int i = 0; i < CHL; i++) {
    float4 dt4 = *(const float4*)(dtsb + (size_t)(k * Lc + l0 + i) * 4);
    float v = db + dw0 * dt4.x + dw1 * dt4.y + dw2 * dt4.z + dw3 * dt4.w;
    float t = softplusf(v);
    float xv = xact[(idx0 + st * i) * DIc + d];
    dtv[i] = t;
    dtx[i] = t * xv;
    acc[i] = (sh == 0) ? Dv * xv : 0.f;  // D*x folded once per (i, dir)
  }
  __syncthreads();
  const float4* B4 = (const float4*)sB[dir];
  const float4* C4 = (const float4*)sC[dir];
#pragma unroll
  for (int i = 0; i < CHL; i++) {
    float4 Bg0 = B4[i * 4 + sh * 2];
    float4 Bg1 = B4[i * 4 + sh * 2 + 1];
    float4 Cg0 = C4[i * 4 + sh * 2];
    float4 Cg1 = C4[i * 4 + sh * 2 + 1];
    float t = dtv[i], tx = dtx[i];
    float a = acc[i];
#define STEP(hh, bb, cc, aa2) { float da = fexp2(t * (aa2)); hh = da * hh + tx * (bb); a += hh * (cc); }
    STEP(h[0], Bg0.x, Cg0.x, A2[0]);
    STEP(h[1], Bg0.y, Cg0.y, A2[1]);
    STEP(h[2], Bg0.z, Cg0.z, A2[2]);
    STEP(h[3], Bg0.w, Cg0.w, A2[3]);
    STEP(h[4], Bg1.x, Cg1.x, A2[4]);
    STEP(h[5], Bg1.y, Cg1.y, A2[5]);
    STEP(h[6], Bg1.z, Cg1.z, A2[6]);
    STEP(h[7], Bg1.w, Cg1.w, A2[7]);
#undef STEP
    acc[i] = a;
  }
  // combine: sh1 writes, sh0 adds, wave0 merges dirs (dir1 pixel i' = CHL-1-i)
  if (sh == 1) {
#pragma unroll
    for (int i = 0; i < CHL; i++) yred[dir][i][dm] = acc[i];
  }
  __syncthreads();
  if (sh == 0) {
#pragma unroll
    for (int i = 0; i < CHL; i++) yred[dir][i][dm] += acc[i];
  }
  __syncthreads();
  if (sh == 0 && dir == 0) {
#pragma unroll
    for (int i = 0; i < CHL; i++)
      ypair[(size_t)(idx0 + st * i) * DIc + d] =
          yred[0][i][dm] + yred[1][CHL - 1 - i][dm];
  }
}

// ---------------------------------------------------------------------------
// bias-branch epilogue: combine pairs + LN + silu(z) + out-proj -> biasb[slot].
// grid (576, 4). y gather is 2 contiguous streams (pairs pre-combined).
__global__ __launch_bounds__(256) void g_out_bias(Params p) {
  __shared__ float yy[4][DIc];
  __shared__ float ml[4][DIc];
  __shared__ float mnv[4], isv[4];
  int tid = threadIdx.x;
  int slot = blockIdx.y;
  float* ws = p.ws;
  float* base = ws + (size_t)slot * SLOTF;
  const float* y01 = base + OFF_Y;
  const float* y23 = base + OFF_Y + Lc * DIc;
  const float* zb = base + OFF_Z;
  const float* owT = ws + OFF_TW + TW_OW + 128 * 64;  // branch 1
  float* biasb = ws + OFF_BIAS;
  int l0 = blockIdx.x * 4;
  for (int it = tid; it < 4 * DIc; it += 256) {
    int d = it & (DIc - 1), pp = it >> 7;
    size_t off = (size_t)(l0 + pp) * DIc + d;
    yy[pp][d] = y01[off] + y23[off];
  }
  __syncthreads();
  {
    int wv = tid >> 6, c = tid & 63;
    float a = yy[wv][c], b = yy[wv][c + 64];
    float s1 = wsum(a + b);
    float s2 = wsum(a * a + b * b);
    float mu = s1 * (1.f / 128.f);
    float var = s2 * (1.f / 128.f) - mu * mu;
    if (c == 0) { mnv[wv] = mu; isv[wv] = rsqrtf(var + 1e-6f); }
  }
  __syncthreads();
  for (int it = tid; it < 4 * DIc; it += 256) {
    int d = it & (DIc - 1), pp = it >> 7;
    int l = l0 + pp;
    float m = (yy[pp][d] - mnv[pp]) * isv[pp] * p.onw[DIc + d] + p.onb[DIc + d];
    float zv = zb[l * DIc + d];
    ml[pp][d] = m * zv * sigmoidf(zv);
  }
  __syncthreads();
  {
    int pp = tid >> 6, c = tid & 63;
    int l = l0 + pp;
    float acc = p.ob[Cc + c];
    for (int d2 = 0; d2 < DIc; d2++) acc += owT[d2 * 64 + c] * ml[pp][d2];
    biasb[(slot * Lc + l) * Cc + c] = acc;
  }
}

// ---------------------------------------------------------------------------
// s-branch epilogue (slot 4, branch 0): combine + LN + silu(z) + out-proj,
// state update; if fuse: KL + in-proj for next round; if finalw: write d_out.
__global__ __launch_bounds__(256) void g_out_s(Params p, int targ, int fuse, int finalw,
                                               const float* curb, float* nxtb) {
  __shared__ float yy[4][DIc];
  __shared__ float ml[4][DIc];
  __shared__ float xvs[4][64];
  __shared__ float mnv[4], isv[4];
  int tid = threadIdx.x;
  float* ws = p.ws;
  float* base = ws + (size_t)4 * SLOTF;
  const float* y01 = base + OFF_Y;
  const float* y23 = base + OFF_Y + Lc * DIc;
  const float* zb = base + OFF_Z;
  float* xcpre = base + OFF_XCPRE;
  float* zbuf  = base + OFF_Z;
  const float* owT  = ws + OFF_TW + TW_OW;    // branch 0
  const float* inwT = ws + OFF_TW + TW_INW;   // branch 0
  const float* biasb = ws + OFF_BIAS;
  int l0 = blockIdx.x * 4;
  for (int it = tid; it < 4 * DIc; it += 256) {
    int d = it & (DIc - 1), pp = it >> 7;
    size_t off = (size_t)(l0 + pp) * DIc + d;
    yy[pp][d] = y01[off] + y23[off];
  }
  __syncthreads();
  {
    int wv = tid >> 6, c = tid & 63;
    float a = yy[wv][c], b = yy[wv][c + 64];
    float s1 = wsum(a + b);
    float s2 = wsum(a * a + b * b);
    float mu = s1 * (1.f / 128.f);
    float var = s2 * (1.f / 128.f) - mu * mu;
    if (c == 0) { mnv[wv] = mu; isv[wv] = rsqrtf(var + 1e-6f); }
  }
  __syncthreads();
  for (int it = tid; it < 4 * DIc; it += 256) {
    int d = it & (DIc - 1), pp = it >> 7;
    int l = l0 + pp;
    float m = (yy[pp][d] - mnv[pp]) * isv[pp] * p.onw[d] + p.onb[d];
    float zv = zb[l * DIc + d];
    ml[pp][d] = m * zv * sigmoidf(zv);
  }
  __syncthreads();
  {
    int pp = tid >> 6, c = tid & 63;
    int l = l0 + pp;
    float acc = p.ob[c];
    for (int d2 = 0; d2 < DIc; d2++) acc += owT[d2 * 64 + c] * ml[pp][d2];
    float cv = curb[l * Cc + c];
    float nv = cv * __expf(acc) + biasb[(targ * Lc + l) * Cc + c];
    nxtb[l * Cc + c] = nv;
    if (finalw) p.outp[c * Lc + l] = nv;
    if (fuse) {
      float mp = wmax(cv);
      float sp = wsum(__expf(cv - mp));
      float lp = cv - mp - __logf(sp);
      float mq = wmax(nv);
      float sq = wsum(__expf(nv - mq));
      float lq = nv - mq - __logf(sq);
      xvs[pp][c] = __expf(lp) * (lp - lq);
    }
  }
  if (fuse) {
    __syncthreads();
    int d = tid;
    float acc[4] = {0.f, 0.f, 0.f, 0.f};
    for (int cc = 0; cc < Cc; cc++) {
      float wval = inwT[cc * 256 + d];
#pragma unroll
      for (int pp = 0; pp < 4; pp++) acc[pp] += wval * xvs[pp][cc];
    }
    float bv = p.in_b[d];
    if (d < DIc) {
#pragma unroll
      for (int pp = 0; pp < 4; pp++) xcpre[(l0 + pp) * DIc + d] = acc[pp] + bv;
    } else {
      int dd = d - DIc;
#pragma unroll
      for (int pp = 0; pp < 4; pp++) zbuf[(l0 + pp) * DIc + dd] = acc[pp] + bv;
    }
  }
}

// ---------------------------------------------------------------------------
extern "C" void kernel_launch(void* const* d_in, const int* in_sizes, int n_in,
                              void* d_out, int out_size, void* d_ws, size_t ws_size,
                              hipStream_t stream) {
  (void)in_sizes; (void)n_in; (void)out_size; (void)ws_size;
  Params p;
  p.img    = (const float*)d_in[0];
  p.dz     = (const float*)d_in[1];
  p.sigma  = (const float*)d_in[2];
  p.in_w   = (const float*)d_in[3];
  p.in_b   = (const float*)d_in[4];
  p.conv_w = (const float*)d_in[5];
  p.conv_b = (const float*)d_in[6];
  p.xp_w   = (const float*)d_in[7];
  p.dt_w   = (const float*)d_in[8];
  p.dt_b   = (const float*)d_in[9];
  p.A_logs = (const float*)d_in[10];
  p.Ds     = (const float*)d_in[11];
  p.onw    = (const float*)d_in[12];
  p.onb    = (const float*)d_in[13];
  p.ow     = (const float*)d_in[14];
  p.ob     = (const float*)d_in[15];
  p.niw    = (const float*)d_in[16];
  p.nib    = (const float*)d_in[17];
  p.ndw    = (const float*)d_in[18];
  p.ndb    = (const float*)d_in[19];
  p.outp   = (float*)d_out;
  p.ws     = (float*)d_ws;

  // NOTE: cooperative mega-kernel removed — measured 3.4x slower (grid.sync
  // forces cross-XCD L2 flushes: 343 MB HBM traffic vs ~150 MB, VALUBusy 7.6%).
  // NOTE: CT-compression of sumA reverted — tripled scan1 traffic (+35us).

  hipLaunchKernelGGL(g_transpose, dim3(144), dim3(256), 0, stream, p);
  // mega round: bias t=0..3 (slots 0-3) + s-branch t=0 (slot 4, prep fused)
  hipLaunchKernelGGL(g_inproj, dim3(288, 5), dim3(256), 0, stream, p);
  hipLaunchKernelGGL(g_conv, dim3(576, 5), dim3(256), 0, stream, p, 0);
  hipLaunchKernelGGL(g_scan1, dim3(Kc * NCH * 2, 5), dim3(256), 0, stream, p, 0);
  hipLaunchKernelGGL(g_mid, dim3(512, 5), dim3(256), 0, stream, p, 0);
  hipLaunchKernelGGL(g_scan2, dim3(2 * NCH * 2, 5), dim3(256), 0, stream, p, 0);
  hipLaunchKernelGGL(g_out_bias, dim3(576, 4), dim3(256), 0, stream, p);

  float* b1 = p.ws + OFF_B1;
  float* b2 = p.ws + OFF_B2;
  hipLaunchKernelGGL(g_out_s, dim3(576), dim3(256), 0, stream, p, 0, 1, 0,
                     (const float*)b1, b2);
  for (int t = 1; t < Tc; t++) {
    const float* curb = (t & 1) ? b2 : b1;
    float* nxtb       = (t & 1) ? b1 : b2;
    hipLaunchKernelGGL(g_conv, dim3(576, 1), dim3(256), 0, stream, p, 4);
    hipLaunchKernelGGL(g_scan1, dim3(Kc * NCH * 2, 1), dim3(256), 0, stream, p, 4);
    hipLaunchKernelGGL(g_mid, dim3(512, 1), dim3(256), 0, stream, p, 4);
    hipLaunchKernelGGL(g_scan2, dim3(2 * NCH * 2, 1), dim3(256), 0, stream, p, 4);
    hipLaunchKernelGGL(g_out_s, dim3(576), dim3(256), 0, stream, p,
                       t, (t == Tc - 1) ? 0 : 1, (t == Tc - 1) ? 1 : 0, curb, nxtb);
  }
}

// Round 8
// 384.077 us; speedup vs baseline: 1.0728x; 1.0728x over previous
//
#include <hip/hip_runtime.h>

#define DEV __device__ __forceinline__

// Problem constants
constexpr int Cc = 64, DIc = 128, Sc = 16, Rc = 4, Kc = 4;
constexpr int Lc = 2304, Tc = 4;
constexpr int NCH = 144, CHL = 16;  // 144 chunks of 16 (best measured config)

// Workspace layout (float offsets). 5 slots: 0-3 = bias branch t=0..3, 4 = s-branch.
constexpr int OFF_XCPRE = 0;              // L*DI  [l][d]
constexpr int OFF_Z     = 294912;         // L*DI  [l][d]
constexpr int OFF_XACT  = 589824;         // L*DI  [l][d]
constexpr int OFF_DTS   = 884736;         // K*L*R [k][pos][r]  (r contiguous -> float4)
constexpr int OFF_BS    = 921600;         // K*L*S [k][pos][s]
constexpr int OFF_CS    = 1069056;        // K*L*S
constexpr int OFF_Y     = 1216512;        // 2*L*DI [pair][pixel][d] (dir-pairs pre-combined)
constexpr int OFF_SUMA  = 2396160;        // K*NCH*S*DI (lane-major in d)
constexpr int OFF_SUMB  = 3575808;        // K*NCH*S*DI
constexpr int OFF_H0    = 4755456;        // K*NCH*S*DI
constexpr int SLOTF     = 5935104;
constexpr int OFF_B1    = 5 * SLOTF;      // L*C state buffers [l][c]
constexpr int OFF_B2    = OFF_B1 + Lc * Cc;
constexpr int OFF_BIAS  = OFF_B2 + Lc * Cc;       // T*L*C [t][l][c]
// Lane-major transposed weights:
constexpr int OFF_TW    = OFF_BIAS + Tc * Lc * Cc;
constexpr int TW_INW  = 0;        // [2][64][256]
constexpr int TW_XPW  = 32768;    // [2][128][144]
constexpr int TW_OW   = 69632;    // [2][128][64]
constexpr int TW_CW   = 86016;    // [2][9][128]
constexpr int TW_AT   = 88320;    // [2][4][16][128]  (stores A2 = -exp(A_logs)*log2e)
constexpr int TW_DTW  = 104704;   // [2][4][4][128]

struct Params {
  const float *img, *dz, *sigma, *in_w, *in_b, *conv_w, *conv_b, *xp_w, *dt_w,
              *dt_b, *A_logs, *Ds, *onw, *onb, *ow, *ob, *niw, *nib, *ndw, *ndb;
  float* outp;
  float* ws;
};

DEV float wsum(float v) {
#pragma unroll
  for (int m = 32; m; m >>= 1) v += __shfl_xor(v, m, 64);
  return v;
}
DEV float wmax(float v) {
#pragma unroll
  for (int m = 32; m; m >>= 1) v = fmaxf(v, __shfl_xor(v, m, 64));
  return v;
}
DEV float sigmoidf(float x) { return 1.f / (1.f + __expf(-x)); }
DEV float softplusf(float v) { return (v > 20.f) ? v : __logf(1.f + __expf(v)); }
DEV float fexp2(float x) { return __builtin_amdgcn_exp2f(x); }

// scan-position -> row-major pixel index, per direction
DEV int perm_idx(int k, int l) {
  if (k == 0) return l;
  if (k == 1) return (l % 48) * 48 + l / 48;
  if (k == 2) return Lc - 1 - l;
  int pp = Lc - 1 - l;
  return (pp % 48) * 48 + pp / 48;
}

// Within one 16-chunk the pixel index is base + stride*i (48 = 3*16, no wrap).
DEV int perm_stride(int k) {
  return (k == 0) ? 1 : (k == 1) ? 48 : (k == 2) ? -1 : -48;
}

// ---------------------------------------------------------------------------
// one-time: transpose weights into lane-major layouts. grid 144.
__global__ __launch_bounds__(256) void g_transpose(Params p) {
  float* tw = p.ws + OFF_TW;
  int i = blockIdx.x * 256 + threadIdx.x;
  if (i < 32768) {  // inwT
    int d = i & 255, cc = (i >> 8) & 63, b = i >> 14;
    tw[TW_INW + i] = p.in_w[(b * 256 + d) * 64 + cc];
  }
  if (i < 36864) {  // xpwT
    int kr = i % 144, cc = (i / 144) & 127, b = i / (144 * 128);
    tw[TW_XPW + i] = p.xp_w[(b * 144 + kr) * 128 + cc];
  }
  if (i < 16384) {  // owT
    int c = i & 63, d = (i >> 6) & 127, b = i >> 13;
    tw[TW_OW + i] = p.ow[(b * 64 + c) * 128 + d];
  }
  if (i < 2304) {   // cwT
    int d = i & 127, kk = (i >> 7) % 9, b = i / 1152;
    tw[TW_CW + i] = p.conv_w[(b * 128 + d) * 9 + kk];
  }
  if (i < 16384) {  // A2 = -exp(A_logs) * log2(e)  (exp2-folded)
    int d = i & 127, bks = i >> 7;
    int s = bks & 15, bk = bks >> 4;
    tw[TW_AT + i] = -__expf(p.A_logs[(bk * 128 + d) * 16 + s]) * 1.4426950408889634f;
  }
  if (i < 4096) {   // dtwT
    int d = i & 127, bkr = i >> 7;
    int r = bkr & 3, bk = bkr >> 2;
    tw[TW_DTW + i] = p.dt_w[(bk * 128 + d) * 4 + r];
  }
}

// ---------------------------------------------------------------------------
// mega input projection, grid (288, 5). slots 0-3: x = LN_c(img[slot]) (branch 1);
// slot 4: fused prep — pv = LN_c(dz), cv = pv*exp(sigma) -> B1, x = KL(cv, pv).
__global__ __launch_bounds__(256) void g_inproj(Params p) {
  __shared__ float xv[8][64];
  int tid = threadIdx.x;
  int slot = blockIdx.y;
  int branch = (slot >= 4) ? 0 : 1;
  float* ws = p.ws;
  float* base = ws + (size_t)slot * SLOTF;
  float* xcpre = base + OFF_XCPRE;
  float* zbuf  = base + OFF_Z;
  const float* wT = ws + OFF_TW + TW_INW + branch * 64 * 256;
  int l0 = blockIdx.x * 8;
  int wv = tid >> 6, c = tid & 63;
#pragma unroll
  for (int q = 0; q < 2; q++) {
    int pp = wv * 2 + q;
    int l = l0 + pp;
    float x;
    if (branch == 1) {
      float v = p.img[(slot * Cc + c) * Lc + l];
      float mu = wsum(v) * (1.f / 64.f);
      float var = wsum(v * v) * (1.f / 64.f) - mu * mu;
      x = (v - mu) * rsqrtf(var + 1e-6f) * p.niw[c] + p.nib[c];
    } else {
      // fused prep: prev = LN_c(dz), cur = prev*exp(sigma)
      float v = p.dz[c * Lc + l];
      float mu = wsum(v) * (1.f / 64.f);
      float var = wsum(v * v) * (1.f / 64.f) - mu * mu;
      float pv = (v - mu) * rsqrtf(var + 1e-6f) * p.ndw[c] + p.ndb[c];
      float cv = pv * __expf(p.sigma[c * Lc + l]);
      (ws + OFF_B1)[l * Cc + c] = cv;
      float mp = wmax(pv);
      float sp = wsum(__expf(pv - mp));
      float lp = pv - mp - __logf(sp);
      float mq = wmax(cv);
      float sq = wsum(__expf(cv - mq));
      float lq = cv - mq - __logf(sq);
      x = __expf(lp) * (lp - lq);
    }
    xv[pp][c] = x;
  }
  __syncthreads();
  int d = tid;
  float acc[8];
#pragma unroll
  for (int q = 0; q < 8; q++) acc[q] = 0.f;
  for (int cc = 0; cc < Cc; cc++) {
    float wval = wT[cc * 256 + d];
#pragma unroll
    for (int q = 0; q < 8; q++) acc[q] += wval * xv[q][cc];
  }
  float bv = p.in_b[branch * 2 * DIc + d];
  if (d < DIc) {
#pragma unroll
    for (int q = 0; q < 8; q++) xcpre[(l0 + q) * DIc + d] = acc[q] + bv;
  } else {
    int dd = d - DIc;
#pragma unroll
    for (int q = 0; q < 8; q++) zbuf[(l0 + q) * DIc + dd] = acc[q] + bv;
  }
}

// ---------------------------------------------------------------------------
// depthwise conv3x3 + silu -> xact; xp proj -> dts/Bs/Cs. grid (576, nslots).
__global__ __launch_bounds__(256) void g_conv(Params p, int slot_base) {
  __shared__ float xv[4][DIc];
  int tid = threadIdx.x;
  int slot = slot_base + blockIdx.y;
  int branch = (slot >= 4) ? 0 : 1;
  float* ws = p.ws;
  float* base = ws + (size_t)slot * SLOTF;
  float* xcpre = base + OFF_XCPRE;
  float* xact  = base + OFF_XACT;
  float* dtsb  = base + OFF_DTS;
  float* Bsb   = base + OFF_BS;
  float* Csb   = base + OFF_CS;
  const float* cwT  = ws + OFF_TW + TW_CW + branch * 9 * 128;
  const float* xpwT = ws + OFF_TW + TW_XPW + branch * 128 * 144;
  int h = blockIdx.x / 12;
  int w0 = (blockIdx.x % 12) * 4;
  for (int it = tid; it < 4 * DIc; it += 256) {
    int d = it & (DIc - 1);
    int pp = it >> 7;
    int w = w0 + pp;
    float acc = 0.f;
#pragma unroll
    for (int kh = 0; kh < 3; kh++) {
      int hh = h + kh - 1;
      if ((unsigned)hh < 48u) {
#pragma unroll
        for (int kw = 0; kw < 3; kw++) {
          int wp = w + kw - 1;
          if ((unsigned)wp < 48u)
            acc += cwT[(kh * 3 + kw) * 128 + d] * xcpre[(hh * 48 + wp) * DIc + d];
        }
      }
    }
    float v = acc + p.conv_b[branch * DIc + d];
    float s = v * sigmoidf(v);
    xv[pp][d] = s;
    xact[(h * 48 + w) * DIc + d] = s;
  }
  __syncthreads();
  if (tid < Kc * 36) {
    int k = tid / 36, r = tid % 36;
    float acc[4] = {0.f, 0.f, 0.f, 0.f};
    for (int cc = 0; cc < DIc; cc++) {
      float wvv = xpwT[cc * 144 + tid];
#pragma unroll
      for (int pp = 0; pp < 4; pp++) acc[pp] += wvv * xv[pp][cc];
    }
#pragma unroll
    for (int pp = 0; pp < 4; pp++) {
      int w = w0 + pp;
      int lr = h * 48 + w, lcx = w * 48 + h;
      int pos = (k == 0) ? lr : (k == 1) ? lcx : (k == 2) ? (Lc - 1 - lr) : (Lc - 1 - lcx);
      if (r < Rc) dtsb[(k * Lc + pos) * Rc + r] = acc[pp];
      else if (r < Rc + Sc) Bsb[(k * Lc + pos) * Sc + (r - Rc)] = acc[pp];
      else Csb[(k * Lc + pos) * Sc + (r - Rc - Sc)] = acc[pp];
    }
  }
}

// ---------------------------------------------------------------------------
// scan pass 1: per-chunk summaries, s-split x2. Block = (k,ch,shb): 128 d x
// 2 s-quarters; each thread owns 4 s-states.
// Grid (K*NCH*2 = 1152, nslots). LDS 1KB.
__global__ __launch_bounds__(256, 4) void g_scan1(Params p, int slot_base) {
  __shared__ alignas(16) float sB[CHL * Sc];  // 1KB
  int tid = threadIdx.x;
  int slot = slot_base + blockIdx.y;
  int branch = (slot >= 4) ? 0 : 1;
  float* ws = p.ws;
  float* base = ws + (size_t)slot * SLOTF;
  const float* xact = base + OFF_XACT;
  const float* Bsb  = base + OFF_BS;
  const float* dtsb = base + OFF_DTS;
  float* sumA = base + OFF_SUMA;
  float* sumB = base + OFF_SUMB;
  int bx = blockIdx.x;
  int shb = bx & 1;
  int kch = bx >> 1;
  int k = kch / NCH, ch = kch - k * NCH;
  int d = tid & (DIc - 1);
  int sq = tid >> 7;
  int s0 = shb * 8 + sq * 4;  // this thread's 4 s-states
  int bk = branch * Kc + k;
  const float* AT   = ws + OFF_TW + TW_AT;
  const float* dtwT = ws + OFF_TW + TW_DTW;
  int l0 = ch * CHL;
  // stage chunk B (one coalesced 1KB load)
  sB[tid] = Bsb[(k * Lc + l0) * Sc + tid];
  float A2[4];
#pragma unroll
  for (int j = 0; j < 4; j++) A2[j] = AT[(bk * 16 + s0 + j) * 128 + d];
  float dw0 = dtwT[(bk * 4 + 0) * 128 + d];
  float dw1 = dtwT[(bk * 4 + 1) * 128 + d];
  float dw2 = dtwT[(bk * 4 + 2) * 128 + d];
  float dw3 = dtwT[(bk * 4 + 3) * 128 + d];
  float db = p.dt_b[bk * DIc + d];
  int idx0 = perm_idx(k, l0);
  int st = perm_stride(k);
  float dtv[CHL], dtx[CHL];
  float CT = 0.f;
#pragma unroll
  for (int i = 0; i < CHL; i++) {
    float4 dt4 = *(const float4*)(dtsb + (size_t)(k * Lc + l0 + i) * 4);
    float v = db + dw0 * dt4.x + dw1 * dt4.y + dw2 * dt4.z + dw3 * dt4.w;
    float t = softplusf(v);
    dtv[i] = t;
    dtx[i] = t * xact[(idx0 + st * i) * DIc + d];
    CT += t;
  }
  __syncthreads();
  const float4* B4 = (const float4*)sB;
  float h[4];
#pragma unroll
  for (int j = 0; j < 4; j++) h[j] = 0.f;
#pragma unroll
  for (int i = 0; i < CHL; i++) {
    float4 Bg = B4[i * 4 + (s0 >> 2)];
    float t = dtv[i], tx = dtx[i];
#define STEP1(hh, bb, aa2) { float da = fexp2(t * (aa2)); hh = da * hh + tx * (bb); }
    STEP1(h[0], Bg.x, A2[0]);
    STEP1(h[1], Bg.y, A2[1]);
    STEP1(h[2], Bg.z, A2[2]);
    STEP1(h[3], Bg.w, A2[3]);
#undef STEP1
  }
  float* sa = sumA + ((size_t)(k * NCH + ch) * Sc + s0) * DIc + d;
  float* sb = sumB + ((size_t)(k * NCH + ch) * Sc + s0) * DIc + d;
#pragma unroll
  for (int j = 0; j < 4; j++) sa[j * DIc] = fexp2(A2[j] * CT);  // == prod_i da_i
#pragma unroll
  for (int j = 0; j < 4; j++) sb[j * DIc] = h[j];
}

// ---------------------------------------------------------------------------
// scan mid, parallelized: chain of 144 = 8 groups x 18. Block = 256 thr
// (32 d-lanes x 8 groups). Per thread: serial 18-aggregate, Kogge-Stone over
// 8 group aggregates in LDS (3 steps), re-scan 18 from registers.
// Grid (Kc*Sc*4 dblk = 256, nslots) — 8x blocks, depth 144 -> ~39.
__global__ __launch_bounds__(256) void g_mid(Params p, int slot_base) {
  __shared__ float sA[8][33], sBs[8][33];
  int tid = threadIdx.x;
  int slot = slot_base + blockIdx.y;
  float* base = p.ws + (size_t)slot * SLOTF;
  const float* sumA = base + OFF_SUMA;
  const float* sumB = base + OFF_SUMB;
  float* h0 = base + OFF_H0;
  int bx = blockIdx.x;     // k*64 + s*4 + dblk
  int k = bx >> 6;
  int s = (bx >> 2) & 15;
  int dblk = bx & 3;
  int dl = tid & 31;
  int g = tid >> 5;        // group 0..7 (18 chunks each)
  int d = dblk * 32 + dl;
  float a[18], b[18];
#pragma unroll
  for (int j = 0; j < 18; j++) {
    size_t idx = ((size_t)(k * NCH + g * 18 + j) * Sc + s) * DIc + d;
    a[j] = sumA[idx];
    b[j] = sumB[idx];
  }
  // group aggregate (apply chunks in order): h' = Ag*h + Bg
  float Ag = 1.f, Bg = 0.f;
#pragma unroll
  for (int j = 0; j < 18; j++) { Bg = a[j] * Bg + b[j]; Ag *= a[j]; }
  sA[g][dl] = Ag; sBs[g][dl] = Bg;
  __syncthreads();
  // inclusive Kogge-Stone over groups: new = agg[g-off] then agg[g]
  float Ai = Ag, Bi = Bg;
#pragma unroll
  for (int off = 1; off < 8; off <<= 1) {
    float Ap = 1.f, Bp = 0.f;
    bool take = (g >= off);
    if (take) { Ap = sA[g - off][dl]; Bp = sBs[g - off][dl]; }
    __syncthreads();
    if (take) {
      Bi = Ai * Bp + Bi;
      Ai = Ai * Ap;
      sA[g][dl] = Ai; sBs[g][dl] = Bi;
    }
    __syncthreads();
  }
  // exclusive prefix applied to h_init=0 -> B_inclusive(g-1)
  float h = (g == 0) ? 0.f : sBs[g - 1][dl];
#pragma unroll
  for (int j = 0; j < 18; j++) {
    size_t idx = ((size_t)(k * NCH + g * 18 + j) * Sc + s) * DIc + d;
    h0[idx] = h;
    h = a[j] * h + b[j];
  }
}

// ---------------------------------------------------------------------------
// scan pass 2: dir-pair merged, d split in half. Block = 256 thr
// (64 d x 2 sh x 2 dir), wave-aligned roles. Grid (2 pair x NCH x 2 dblk
// = 576, nslots). LDS 12KB; dtv/dtx recomputed per thread.
__global__ __launch_bounds__(256, 4) void g_scan2(Params p, int slot_base) {
  __shared__ alignas(16) float sB[2][CHL * Sc];   // 2KB
  __shared__ alignas(16) float sC[2][CHL * Sc];   // 2KB
  __shared__ alignas(16) float yred[2][CHL][64];  // 8KB
  int tid = threadIdx.x;
  int slot = slot_base + blockIdx.y;
  int branch = (slot >= 4) ? 0 : 1;
  float* ws = p.ws;
  float* base = ws + (size_t)slot * SLOTF;
  const float* xact = base + OFF_XACT;
  const float* Bsb  = base + OFF_BS;
  const float* Csb  = base + OFF_CS;
  const float* dtsb = base + OFF_DTS;
  const float* h0b  = base + OFF_H0;
  int bx = blockIdx.x;
  int pair = bx / (2 * NCH);
  int rem = bx - pair * 2 * NCH;
  int chA = rem >> 1;
  int dblk = rem & 1;
  int dm = tid & 63;
  int d = dblk * 64 + dm;
  int sh = (tid >> 6) & 1;
  int dir = tid >> 7;
  int kA = pair, kB = pair + 2;
  int l0A = chA * CHL, l0B = (NCH - 1 - chA) * CHL;
  // stage both dirs' B/C (4 coalesced 1KB loads)
  sB[0][tid] = Bsb[(kA * Lc + l0A) * Sc + tid];
  sB[1][tid] = Bsb[(kB * Lc + l0B) * Sc + tid];
  sC[0][tid] = Csb[(kA * Lc + l0A) * Sc + tid];
  sC[1][tid] = Csb[(kB * Lc + l0B) * Sc + tid];
  int k = dir ? kB : kA;
  int ch = dir ? (NCH - 1 - chA) : chA;
  int bk = branch * Kc + k;
  float* ypair = base + OFF_Y + (size_t)pair * Lc * DIc;
  const float* AT   = ws + OFF_TW + TW_AT;
  const float* dtwT = ws + OFF_TW + TW_DTW;
  int l0 = ch * CHL;
  float A2[8];
#pragma unroll
  for (int j = 0; j < 8; j++) A2[j] = AT[(bk * 16 + sh * 8 + j) * 128 + d];
  float h[8];
  {
    const float* hp = h0b + ((size_t)(k * NCH + ch) * Sc + sh * 8) * DIc + d;
#pragma unroll
    for (int j = 0; j < 8; j++) h[j] = hp[j * DIc];
  }
  float dw0 = dtwT[(bk * 4 + 0) * 128 + d];
  float dw1 = dtwT[(bk * 4 + 1) * 128 + d];
  float dw2 = dtwT[(bk * 4 + 2) * 128 + d];
  float dw3 = dtwT[(bk * 4 + 3) * 128 + d];
  float db = p.dt_b[bk * DIc + d];
  float Dv = p.Ds[bk * DIc + d];
  int idx0 = perm_idx(k, l0);
  int st = perm_stride(k);
  float dtv[CHL], dtx[CHL], acc[CHL];
#pragma unroll
  for (int i = 0; i < CHL; i++) {
    float4 dt4 = *(const float4*)(dtsb + (size_t)(k * Lc + l0 + i) * 4);
    float v = db + dw0 * dt4.x + dw1 * dt4.y + dw2 * dt4.z + dw3 * dt4.w;
    float t = softplusf(v);
    float xv = xact[(idx0 + st * i) * DIc + d];
    dtv[i] = t;
    dtx[i] = t * xv;
    acc[i] = (sh == 0) ? Dv * xv : 0.f;  // D*x folded once per (i, dir)
  }
  __syncthreads();
  const float4* B4 = (const float4*)sB[dir];
  const float4* C4 = (const float4*)sC[dir];
#pragma unroll
  for (int i = 0; i < CHL; i++) {
    float4 Bg0 = B4[i * 4 + sh * 2];
    float4 Bg1 = B4[i * 4 + sh * 2 + 1];
    float4 Cg0 = C4[i * 4 + sh * 2];
    float4 Cg1 = C4[i * 4 + sh * 2 + 1];
    float t = dtv[i], tx = dtx[i];
    float a = acc[i];
#define STEP(hh, bb, cc, aa2) { float da = fexp2(t * (aa2)); hh = da * hh + tx * (bb); a += hh * (cc); }
    STEP(h[0], Bg0.x, Cg0.x, A2[0]);
    STEP(h[1], Bg0.y, Cg0.y, A2[1]);
    STEP(h[2], Bg0.z, Cg0.z, A2[2]);
    STEP(h[3], Bg0.w, Cg0.w, A2[3]);
    STEP(h[4], Bg1.x, Cg1.x, A2[4]);
    STEP(h[5], Bg1.y, Cg1.y, A2[5]);
    STEP(h[6], Bg1.z, Cg1.z, A2[6]);
    STEP(h[7], Bg1.w, Cg1.w, A2[7]);
#undef STEP
    acc[i] = a;
  }
  // combine: sh1 writes, sh0 adds, wave0 merges dirs (dir1 pixel i' = 15-i)
  if (sh == 1) {
#pragma unroll
    for (int i = 0; i < CHL; i++) yred[dir][i][dm] = acc[i];
  }
  __syncthreads();
  if (sh == 0) {
#pragma unroll
    for (int i = 0; i < CHL; i++) yred[dir][i][dm] += acc[i];
  }
  __syncthreads();
  if (sh == 0 && dir == 0) {
#pragma unroll
    for (int i = 0; i < CHL; i++)
      ypair[(size_t)(idx0 + st * i) * DIc + d] =
          yred[0][i][dm] + yred[1][CHL - 1 - i][dm];
  }
}

// ---------------------------------------------------------------------------
// bias-branch epilogue: combine pairs + LN + silu(z) + out-proj -> biasb[slot].
// grid (576, 4). y gather is 2 contiguous streams (pairs pre-combined).
__global__ __launch_bounds__(256) void g_out_bias(Params p) {
  __shared__ float yy[4][DIc];
  __shared__ float ml[4][DIc];
  __shared__ float mnv[4], isv[4];
  int tid = threadIdx.x;
  int slot = blockIdx.y;
  float* ws = p.ws;
  float* base = ws + (size_t)slot * SLOTF;
  const float* y01 = base + OFF_Y;
  const float* y23 = base + OFF_Y + Lc * DIc;
  const float* zb = base + OFF_Z;
  const float* owT = ws + OFF_TW + TW_OW + 128 * 64;  // branch 1
  float* biasb = ws + OFF_BIAS;
  int l0 = blockIdx.x * 4;
  for (int it = tid; it < 4 * DIc; it += 256) {
    int d = it & (DIc - 1), pp = it >> 7;
    size_t off = (size_t)(l0 + pp) * DIc + d;
    yy[pp][d] = y01[off] + y23[off];
  }
  __syncthreads();
  {
    int wv = tid >> 6, c = tid & 63;
    float a = yy[wv][c], b = yy[wv][c + 64];
    float s1 = wsum(a + b);
    float s2 = wsum(a * a + b * b);
    float mu = s1 * (1.f / 128.f);
    float var = s2 * (1.f / 128.f) - mu * mu;
    if (c == 0) { mnv[wv] = mu; isv[wv] = rsqrtf(var + 1e-6f); }
  }
  __syncthreads();
  for (int it = tid; it < 4 * DIc; it += 256) {
    int d = it & (DIc - 1), pp = it >> 7;
    int l = l0 + pp;
    float m = (yy[pp][d] - mnv[pp]) * isv[pp] * p.onw[DIc + d] + p.onb[DIc + d];
    float zv = zb[l * DIc + d];
    ml[pp][d] = m * zv * sigmoidf(zv);
  }
  __syncthreads();
  {
    int pp = tid >> 6, c = tid & 63;
    int l = l0 + pp;
    float acc = p.ob[Cc + c];
    for (int d2 = 0; d2 < DIc; d2++) acc += owT[d2 * 64 + c] * ml[pp][d2];
    biasb[(slot * Lc + l) * Cc + c] = acc;
  }
}

// ---------------------------------------------------------------------------
// s-branch epilogue (slot 4, branch 0): combine + LN + silu(z) + out-proj,
// state update; if fuse: KL + in-proj for next round; if finalw: write d_out.
__global__ __launch_bounds__(256) void g_out_s(Params p, int targ, int fuse, int finalw,
                                               const float* curb, float* nxtb) {
  __shared__ float yy[4][DIc];
  __shared__ float ml[4][DIc];
  __shared__ float xvs[4][64];
  __shared__ float mnv[4], isv[4];
  int tid = threadIdx.x;
  float* ws = p.ws;
  float* base = ws + (size_t)4 * SLOTF;
  const float* y01 = base + OFF_Y;
  const float* y23 = base + OFF_Y + Lc * DIc;
  const float* zb = base + OFF_Z;
  float* xcpre = base + OFF_XCPRE;
  float* zbuf  = base + OFF_Z;
  const float* owT  = ws + OFF_TW + TW_OW;    // branch 0
  const float* inwT = ws + OFF_TW + TW_INW;   // branch 0
  const float* biasb = ws + OFF_BIAS;
  int l0 = blockIdx.x * 4;
  for (int it = tid; it < 4 * DIc; it += 256) {
    int d = it & (DIc - 1), pp = it >> 7;
    size_t off = (size_t)(l0 + pp) * DIc + d;
    yy[pp][d] = y01[off] + y23[off];
  }
  __syncthreads();
  {
    int wv = tid >> 6, c = tid & 63;
    float a = yy[wv][c], b = yy[wv][c + 64];
    float s1 = wsum(a + b);
    float s2 = wsum(a * a + b * b);
    float mu = s1 * (1.f / 128.f);
    float var = s2 * (1.f / 128.f) - mu * mu;
    if (c == 0) { mnv[wv] = mu; isv[wv] = rsqrtf(var + 1e-6f); }
  }
  __syncthreads();
  for (int it = tid; it < 4 * DIc; it += 256) {
    int d = it & (DIc - 1), pp = it >> 7;
    int l = l0 + pp;
    float m = (yy[pp][d] - mnv[pp]) * isv[pp] * p.onw[d] + p.onb[d];
    float zv = zb[l * DIc + d];
    ml[pp][d] = m * zv * sigmoidf(zv);
  }
  __syncthreads();
  {
    int pp = tid >> 6, c = tid & 63;
    int l = l0 + pp;
    float acc = p.ob[c];
    for (int d2 = 0; d2 < DIc; d2++) acc += owT[d2 * 64 + c] * ml[pp][d2];
    float cv = curb[l * Cc + c];
    float nv = cv * __expf(acc) + biasb[(targ * Lc + l) * Cc + c];
    nxtb[l * Cc + c] = nv;
    if (finalw) p.outp[c * Lc + l] = nv;
    if (fuse) {
      float mp = wmax(cv);
      float sp = wsum(__expf(cv - mp));
      float lp = cv - mp - __logf(sp);
      float mq = wmax(nv);
      float sq = wsum(__expf(nv - mq));
      float lq = nv - mq - __logf(sq);
      xvs[pp][c] = __expf(lp) * (lp - lq);
    }
  }
  if (fuse) {
    __syncthreads();
    int d = tid;
    float acc[4] = {0.f, 0.f, 0.f, 0.f};
    for (int cc = 0; cc < Cc; cc++) {
      float wval = inwT[cc * 256 + d];
#pragma unroll
      for (int pp = 0; pp < 4; pp++) acc[pp] += wval * xvs[pp][cc];
    }
    float bv = p.in_b[d];
    if (d < DIc) {
#pragma unroll
      for (int pp = 0; pp < 4; pp++) xcpre[(l0 + pp) * DIc + d] = acc[pp] + bv;
    } else {
      int dd = d - DIc;
#pragma unroll
      for (int pp = 0; pp < 4; pp++) zbuf[(l0 + pp) * DIc + dd] = acc[pp] + bv;
    }
  }
}

// ---------------------------------------------------------------------------
extern "C" void kernel_launch(void* const* d_in, const int* in_sizes, int n_in,
                              void* d_out, int out_size, void* d_ws, size_t ws_size,
                              hipStream_t stream) {
  (void)in_sizes; (void)n_in; (void)out_size; (void)ws_size;
  Params p;
  p.img    = (const float*)d_in[0];
  p.dz     = (const float*)d_in[1];
  p.sigma  = (const float*)d_in[2];
  p.in_w   = (const float*)d_in[3];
  p.in_b   = (const float*)d_in[4];
  p.conv_w = (const float*)d_in[5];
  p.conv_b = (const float*)d_in[6];
  p.xp_w   = (const float*)d_in[7];
  p.dt_w   = (const float*)d_in[8];
  p.dt_b   = (const float*)d_in[9];
  p.A_logs = (const float*)d_in[10];
  p.Ds     = (const float*)d_in[11];
  p.onw    = (const float*)d_in[12];
  p.onb    = (const float*)d_in[13];
  p.ow     = (const float*)d_in[14];
  p.ob     = (const float*)d_in[15];
  p.niw    = (const float*)d_in[16];
  p.nib    = (const float*)d_in[17];
  p.ndw    = (const float*)d_in[18];
  p.ndb    = (const float*)d_in[19];
  p.outp   = (float*)d_out;
  p.ws     = (float*)d_ws;

  // NOTE: cooperative mega-kernel removed — measured 3.4x slower (grid.sync
  // forces cross-XCD L2 flushes: 343 MB HBM traffic vs ~150 MB, VALUBusy 7.6%).
  // NOTE: CT-compression of sumA reverted — tripled scan1 traffic (+35us).
  // NOTE: CHL=8 (288 chunks) reverted — doubled summary-stream traffic, +28us.

  hipLaunchKernelGGL(g_transpose, dim3(144), dim3(256), 0, stream, p);
  // mega round: bias t=0..3 (slots 0-3) + s-branch t=0 (slot 4, prep fused)
  hipLaunchKernelGGL(g_inproj, dim3(288, 5), dim3(256), 0, stream, p);
  hipLaunchKernelGGL(g_conv, dim3(576, 5), dim3(256), 0, stream, p, 0);
  hipLaunchKernelGGL(g_scan1, dim3(Kc * NCH * 2, 5), dim3(256), 0, stream, p, 0);
  hipLaunchKernelGGL(g_mid, dim3(256, 5), dim3(256), 0, stream, p, 0);
  hipLaunchKernelGGL(g_scan2, dim3(2 * NCH * 2, 5), dim3(256), 0, stream, p, 0);
  hipLaunchKernelGGL(g_out_bias, dim3(576, 4), dim3(256), 0, stream, p);

  float* b1 = p.ws + OFF_B1;
  float* b2 = p.ws + OFF_B2;
  hipLaunchKernelGGL(g_out_s, dim3(576), dim3(256), 0, stream, p, 0, 1, 0,
                     (const float*)b1, b2);
  for (int t = 1; t < Tc; t++) {
    const float* curb = (t & 1) ? b2 : b1;
    float* nxtb       = (t & 1) ? b1 : b2;
    hipLaunchKernelGGL(g_conv, dim3(576, 1), dim3(256), 0, stream, p, 4);
    hipLaunchKernelGGL(g_scan1, dim3(Kc * NCH * 2, 1), dim3(256), 0, stream, p, 4);
    hipLaunchKernelGGL(g_mid, dim3(256, 1), dim3(256), 0, stream, p, 4);
    hipLaunchKernelGGL(g_scan2, dim3(2 * NCH * 2, 1), dim3(256), 0, stream, p, 4);
    hipLaunchKernelGGL(g_out_s, dim3(576), dim3(256), 0, stream, p,
                       t, (t == Tc - 1) ? 0 : 1, (t == Tc - 1) ? 1 : 0, curb, nxtb);
  }
}